// Round 14
// baseline (48.259 us; speedup 1.0000x reference)
//
#include <hip/hip_runtime.h>

// Problem constants
#define N_  16
#define C_  64
#define H_  128
#define W_  128
#define HO_ 64
#define WO_ 64
#define CO_ 18

// WT geometry: 20 rows (18 + 2 zero) x 584 f16
#define BK     584
#define BROWS  20
#define BBYTES_PAD 23424             // ceil(20*584*2/128)*128, pad zeroed
#define NSHORT (BBYTES_PAD/2)
#define SHIFTOFF BBYTES_PAD          // shift[18] fp32 after WT in ws
#define SIGOFF  BBYTES_PAD           // in LDS: sigma buffer after WT copy
#define LDSBYTES (BBYTES_PAD + 64*19*4)   // 23424 + 4864 = 28288 -> 4 blocks/CU

typedef _Float16 f16;
typedef f16 f16x4 __attribute__((ext_vector_type(4)));
typedef float f4v  __attribute__((ext_vector_type(4)));

// ws: [0..23423B)  WT f16 [20][584]: WT[o][tap*64+c] = cw[o,c,tap]*inv[o]
//     (rows>=18, k>=576, pad region all ZERO)
//     [23424B..)   shift fp32 [18] = beta - mean*inv
__global__ void pasa_prep(const float* __restrict__ cw,
                          const float* __restrict__ gamma,
                          const float* __restrict__ beta,
                          const float* __restrict__ mean,
                          const float* __restrict__ var,
                          float* __restrict__ ws)
{
    const int i = blockIdx.x * 256 + threadIdx.x;
    if (i < NSHORT) {
        const int o = i / BK, kk = i % BK;
        unsigned short bits = 0;
        if (o < CO_ && kk < 576) {
            const int tap = kk >> 6, c = kk & 63;   // k = tap*64 + c
            const float inv = gamma[o] * rsqrtf(var[o] + 1e-5f);
            const f16 h = (f16)(cw[o*576 + c*9 + tap] * inv);
            bits = *(const unsigned short*)&h;
        }
        ((unsigned short*)ws)[i] = bits;
    }
    if (i < CO_) {
        const float inv = gamma[i] * rsqrtf(var[i] + 1e-5f);
        *(float*)((char*)ws + SHIFTOFF + i*4) = beta[i] - mean[i] * inv;
    }
}

__global__ __launch_bounds__(512, 8)   // pin VGPR<=64: 8 waves/SIMD, 4 blocks/CU
void pasa_main(const float* __restrict__ x,
               const float* __restrict__ wt,
               float* __restrict__ out)
{
    __shared__ __align__(16) char lds[LDSBYTES];

    const int tid  = threadIdx.x;
    const int lane = tid & 63;
    const int bx = blockIdx.x;
    const int ho = ((bx & 7) << 3) | (bx >> 3);   // XCD-chunk swizzle
    const int n  = blockIdx.y;

    int r0 = 2*ho - 1; if (r0 < 0) r0 = 1;        // reflect pad
    const int r1 = 2*ho, r2 = 2*ho + 1;
    const float* __restrict__ xn = x + (size_t)n * (C_*H_*W_);

    // WT -> LDS (1464 float4s, coalesced; B-reads are wave-broadcast-ish b64)
    {
        const float4* __restrict__ src = (const float4*)wt;
        float4* dst = (float4*)lds;
        #pragma unroll
        for (int it = 0; it < 3; ++it) {
            const int i = tid + it*512;
            if (i < BBYTES_PAD/16) dst[i] = src[i];
        }
    }
    __syncthreads();

    // ---- conv via MFMA, A-fragments gathered DIRECTLY from global x ----
    const int wv = tid >> 6;
    const int mt = wv >> 1, nt = wv & 1;          // 4 M-tiles x 2 N-tiles
    const int p  = lane & 15, lg = lane >> 4;
    const int pos = mt*16 + p;                    // output col 0..63

    const int x0 = 2*pos;
    int xm1 = x0 - 1; if (xm1 < 0) xm1 = 1;       // reflect (pos==0 only)
    const int rows[3] = {r0, r1, r2};

    const int o    = nt*16 + p;
    const int oeff = (o < CO_) ? o : CO_;         // clamp to zeroed row 18
    const char* __restrict__ bb = lds + oeff*(BK*2) + lg*8;

    f4v acc = {0.f, 0.f, 0.f, 0.f};
    #pragma unroll
    for (int ki = 0; ki < 3; ++ki) {
        const float* __restrict__ rp  = xn + rows[ki]*W_;
        const float* __restrict__ am1 = rp + xm1;  // col 2pos-1 (kj=0)
        const float* __restrict__ a01 = rp + x0;   // cols 2pos,2pos+1 (kj=1,2)
        #pragma unroll
        for (int kc = 0; kc < 4; ++kc) {
            const int cb = kc*16 + lg*4;           // this lane's 4 channels
            f16x4 f0, f1, f2;
            #pragma unroll
            for (int i = 0; i < 4; ++i) {
                const size_t co = (size_t)(cb + i) * (H_*W_);
                f0[i] = (f16)am1[co];
                const float2 t = *(const float2*)(a01 + co);  // 8B aligned
                f1[i] = (f16)t.x;
                f2[i] = (f16)t.y;
            }
            const f16x4 b0 = *(const f16x4*)(bb + (ki*3+0)*128 + kc*32);
            const f16x4 b1 = *(const f16x4*)(bb + (ki*3+1)*128 + kc*32);
            const f16x4 b2 = *(const f16x4*)(bb + (ki*3+2)*128 + kc*32);
            acc = __builtin_amdgcn_mfma_f32_16x16x16f16(f0, b0, acc, 0, 0, 0);
            acc = __builtin_amdgcn_mfma_f32_16x16x16f16(f1, b1, acc, 0, 0, 0);
            acc = __builtin_amdgcn_mfma_f32_16x16x16f16(f2, b2, acc, 0, 0, 0);
        }
    }

    // D -> sigma LDS [64 pos][19] (19 coprime 32 -> conflict-light)
    {
        float* sig_lds = (float*)(lds + SIGOFF);
        if (o < CO_) {
            #pragma unroll
            for (int r = 0; r < 4; ++r)
                sig_lds[(mt*16 + lg*4 + r)*19 + o] = acc[r];
        }
    }
    __syncthreads();

    // ---- softmax over 18 (redundant per thread), fp32 ----
    const int wo = tid & 63;
    const int sp = tid >> 6;
    const float* __restrict__ shift = (const float*)((const char*)wt + SHIFTOFF);
    const float* sig_lds = (const float*)(lds + SIGOFF);

    float sig[CO_];
    float mx = -3.4e38f;
    #pragma unroll
    for (int oo = 0; oo < CO_; ++oo) {
        sig[oo] = sig_lds[wo*19 + oo] + shift[oo];
        mx = fmaxf(mx, sig[oo]);
    }
    float sum = 0.f;
    #pragma unroll
    for (int oo = 0; oo < CO_; ++oo) { sig[oo] = __expf(sig[oo] - mx); sum += sig[oo]; }
    const float rs = 1.f / sum;

    float pw[9];
    if ((sp >> 2) == 0) {
        #pragma unroll
        for (int k = 0; k < 9; ++k) pw[k] = sig[k] * rs;
    } else {
        #pragma unroll
        for (int k = 0; k < 9; ++k) pw[k] = sig[9 + k] * rs;
    }

    // ---- aggregation from global fp32 windows (L1/L2-hot), 8 ch/thread ----
    const int c1 = 2*wo;
    int c0 = c1 - 1; if (c0 < 0) c0 = 1;
    #pragma unroll
    for (int j = 0; j < 8; ++j) {
        const int c = sp * 8 + j;
        const float* __restrict__ xc = xn + c * (H_*W_);
        float a = xc[r0*W_ + c0] * pw[0];
        const float2 a12 = *(const float2*)(xc + r0*W_ + c1);
        a = fmaf(a12.x, pw[1], a);
        a = fmaf(a12.y, pw[2], a);
        a = fmaf(xc[r1*W_ + c0], pw[3], a);
        const float2 a45 = *(const float2*)(xc + r1*W_ + c1);
        a = fmaf(a45.x, pw[4], a);
        a = fmaf(a45.y, pw[5], a);
        a = fmaf(xc[r2*W_ + c0], pw[6], a);
        const float2 a78 = *(const float2*)(xc + r2*W_ + c1);
        a = fmaf(a78.x, pw[7], a);
        a = fmaf(a78.y, pw[8], a);
        out[(((size_t)n*C_ + c)*HO_ + ho)*WO_ + wo] = a;
    }
}

extern "C" void kernel_launch(void* const* d_in, const int* in_sizes, int n_in,
                              void* d_out, int out_size, void* d_ws, size_t ws_size,
                              hipStream_t stream) {
    const float* x     = (const float*)d_in[0];
    const float* cw    = (const float*)d_in[1];
    const float* gamma = (const float*)d_in[2];
    const float* beta  = (const float*)d_in[3];
    const float* mean  = (const float*)d_in[4];
    const float* var   = (const float*)d_in[5];
    float* out = (float*)d_out;
    float* ws  = (float*)d_ws;   // needs 23424 + 72 B

    pasa_prep<<<(NSHORT + 255) / 256, 256, 0, stream>>>(cw, gamma, beta, mean, var, ws);
    dim3 grid(HO_, N_);
    pasa_main<<<grid, 512, 0, stream>>>(x, ws, out);
}